// Round 1
// baseline (131.110 us; speedup 1.0000x reference)
//
#include <hip/hip_runtime.h>
#include <hip/hip_bf16.h>

// LIF recurrence: v = tau*v + (1-tau)*x_t ; s = (v > vth) ; v -= s*vth (reset=0)
// B=64, T=256, U=1024 (fp32). Chains independent over (b,u); sequential in t.
// One thread per (b,u): coalesced across u every timestep. Memory-bound.
// Bit-exactness vs numpy fp32: force non-fused mul/add (__fmul_rn/__fadd_rn)
// so the threshold compare (v > 1.0f) sees the same rounding as the reference.

constexpr int kB = 64;
constexpr int kT = 256;
constexpr int kU = 1024;

__global__ __launch_bounds__(256)
void lif_kernel(const float* __restrict__ x, float* __restrict__ out) {
    const int idx = blockIdx.x * blockDim.x + threadIdx.x;   // over B*U
    const int b = idx / kU;
    const int u = idx - b * kU;

    const size_t base = (size_t)b * kT * kU + u;
    const float* __restrict__ xp = x + base;
    float* __restrict__ op = out + base;

    float v = 0.0f;
#pragma unroll 8
    for (int t = 0; t < kT; ++t) {
        const float xt = xp[(size_t)t * kU];
        // v = 0.25*v + 0.75*xt, evaluated as two rn-multiplies + rn-add
        // (matches numpy; prevents FMA contraction at the spike boundary)
        const float a = __fmul_rn(0.25f, v);
        const float c = __fmul_rn(0.75f, xt);
        v = __fadd_rn(a, c);
        const float s = (v > 1.0f) ? 1.0f : 0.0f;
        v = __fsub_rn(v, s);          // s*vth == s exactly; + s*reset adds 0
        op[(size_t)t * kU] = s;
    }
}

extern "C" void kernel_launch(void* const* d_in, const int* in_sizes, int n_in,
                              void* d_out, int out_size, void* d_ws, size_t ws_size,
                              hipStream_t stream) {
    const float* x = (const float*)d_in[0];
    float* out = (float*)d_out;

    const int nthreads = kB * kU;          // 65536 chains
    const int block = 256;
    const int grid = nthreads / block;     // 256 blocks -> ~1 block/CU, 4 waves/CU
    lif_kernel<<<grid, block, 0, stream>>>(x, out);
}

// Round 2
// 109.389 us; speedup vs baseline: 1.1986x; 1.1986x over previous
//
#include <hip/hip_runtime.h>
#include <hip/hip_bf16.h>

// LIF recurrence: v = tau*v + (1-tau)*x_t ; s = (v > vth) ; v -= s (vth=1, reset=0)
// B=64, T=256, U=1024 fp32. One thread per (b,u) chain; coalesced across u.
//
// R1 counters: 48 us, 2 TB/s, occupancy 8.6% -> latency-bound (Little's law:
// 4 waves/CU x 8 outstanding x 4B = 8KB/CU in flight ~= 2 TB/s at ~900cy HBM
// latency). Fix: software-pipeline t in chunks of 16 so each thread keeps 16
// loads in flight (16KB/CU -> not latency-limited). Non-temporal stores keep
// the streamed spike output from evicting the LLC-warm input.
//
// Bit-exactness vs numpy fp32: non-fused __fmul_rn/__fadd_rn so the spike
// compare (v > 1.0f) sees identical rounding to the reference.

constexpr int kB = 64;
constexpr int kT = 256;
constexpr int kU = 1024;
constexpr int kC = 16;              // pipeline chunk (outstanding loads/thread)

__global__ __launch_bounds__(256)
void lif_kernel(const float* __restrict__ x, float* __restrict__ out) {
    const int idx = blockIdx.x * blockDim.x + threadIdx.x;   // over B*U
    const int b = idx >> 10;              // / kU
    const int u = idx & (kU - 1);         // % kU

    const size_t base = (size_t)b * kT * kU + u;
    const float* __restrict__ xp = x + base;
    float* __restrict__ op = out + base;

    float buf[kC];
    // prologue: loads for chunk 0
#pragma unroll
    for (int j = 0; j < kC; ++j)
        buf[j] = xp[(size_t)j * kU];

    float v = 0.0f;
    for (int c = 0; c < kT / kC - 1; ++c) {
        const int t0 = c * kC;
        // issue next chunk's loads first (independent of v-chain)
        float nbuf[kC];
#pragma unroll
        for (int j = 0; j < kC; ++j)
            nbuf[j] = xp[(size_t)(t0 + kC + j) * kU];
        // compute + store current chunk while next loads are in flight
#pragma unroll
        for (int j = 0; j < kC; ++j) {
            const float a = __fmul_rn(0.25f, v);
            const float cc = __fmul_rn(0.75f, buf[j]);
            v = __fadd_rn(a, cc);
            const float s = (v > 1.0f) ? 1.0f : 0.0f;
            v = __fsub_rn(v, s);
            __builtin_nontemporal_store(s, &op[(size_t)(t0 + j) * kU]);
        }
#pragma unroll
        for (int j = 0; j < kC; ++j)
            buf[j] = nbuf[j];
    }
    // epilogue: last chunk
    const int t0 = kT - kC;
#pragma unroll
    for (int j = 0; j < kC; ++j) {
        const float a = __fmul_rn(0.25f, v);
        const float cc = __fmul_rn(0.75f, buf[j]);
        v = __fadd_rn(a, cc);
        const float s = (v > 1.0f) ? 1.0f : 0.0f;
        v = __fsub_rn(v, s);
        __builtin_nontemporal_store(s, &op[(size_t)(t0 + j) * kU]);
    }
}

extern "C" void kernel_launch(void* const* d_in, const int* in_sizes, int n_in,
                              void* d_out, int out_size, void* d_ws, size_t ws_size,
                              hipStream_t stream) {
    const float* x = (const float*)d_in[0];
    float* out = (float*)d_out;

    const int nthreads = kB * kU;          // 65536 chains
    const int block = 256;
    const int grid = nthreads / block;     // 256 blocks -> 1 block/CU, 4 waves/CU
    lif_kernel<<<grid, block, 0, stream>>>(x, out);
}